// Round 8
// baseline (177.886 us; speedup 1.0000x reference)
//
#include <hip/hip_runtime.h>
#include <hip/hip_bf16.h>

// GCN: out = GCNConv2( relu( GCNConv1(x) ) )
// Round 7->8: dimension-sliced, XCD-pinned aggregation.
//   h stored slice-major h_sl[8][NN][rw] (slice s = dims [s*12,(s+1)*12) for D=96,
//   [s*6,(s+1)*6) for D=48; rows padded to 32B/16B). Aggregation grid arranged so
//   blockIdx%8 == slice -> de-facto round-robin puts slice s on XCD s; per-XCD
//   working set 1.6MB fits the 4MB L2. Kills the 8x-XCD fill (77MB -> ~13MB).
//   src_sorted stored as uint16 (NN<65536) since it's re-read by all 8 slices.

constexpr int NN = 50000;
constexpr int NE = 800000;
constexpr int DI = 96;
constexpr int DH = 96;
constexpr int DO = 48;

constexpr int BK_SHIFT = 6;                  // 64 dst nodes per bucket
constexpr int NBK      = (NN + 63) >> 6;     // 782 buckets, ~1023 edges each
constexpr int BK_CAP   = 2048;               // >> max bucket load

constexpr int NCHUNK = 128;                  // blocks in hist/scatter
constexpr int CH     = (NE + NCHUNK - 1) / NCHUNK;  // 6250 edges per chunk

typedef unsigned short us4 __attribute__((ext_vector_type(4)));
typedef unsigned short us8 __attribute__((ext_vector_type(8)));

__device__ __forceinline__ float bf2f(unsigned short u) {
    return __uint_as_float(((unsigned int)u) << 16);
}
__device__ __forceinline__ unsigned short f2bf(float f) {
    __hip_bfloat16 b = __float2bfloat16(f);
    return *reinterpret_cast<unsigned short*>(&b);
}

// ---------------- CSR build (atomic-free multisplit) ----------------

__global__ __launch_bounds__(256) void k_hist(const int* __restrict__ dst,
                                              int* __restrict__ C, int e) {
    __shared__ int hist[NBK];
    for (int i = threadIdx.x; i < NBK; i += 256) hist[i] = 0;
    __syncthreads();
    const int blk = blockIdx.x;
    const int beg = blk * CH, end = min(beg + CH, e);
    for (int i = beg + threadIdx.x; i < end; i += 256)
        atomicAdd(&hist[dst[i] >> BK_SHIFT], 1);
    __syncthreads();
    for (int b = threadIdx.x; b < NBK; b += 256)
        C[b * NCHUNK + blk] = hist[b];
}

__global__ __launch_bounds__(256) void k_rowscan(int* __restrict__ C,
                                                 int* __restrict__ totals,
                                                 int* __restrict__ row_ptr) {
    if (blockIdx.x == 0 && threadIdx.x == 0) row_ptr[NN] = NE;  // sentinel
    const int w    = threadIdx.x >> 6;
    const int lane = threadIdx.x & 63;
    const int r    = blockIdx.x * 4 + w;
    if (r >= NBK) return;
    int* row = C + r * NCHUNK;
    const int v0 = row[lane];
    const int v1 = row[64 + lane];
    int s0 = v0, s1 = v1;
#pragma unroll
    for (int off = 1; off < 64; off <<= 1) {
        int y0 = __shfl_up(s0, off);
        int y1 = __shfl_up(s1, off);
        if (lane >= off) { s0 += y0; s1 += y1; }
    }
    s1 += __shfl(s0, 63);
    row[lane]      = s0 - v0;
    row[64 + lane] = s1 - v1;
    if (lane == 63) totals[r] = s1;
}

__global__ __launch_bounds__(256) void k_scatter(const int* __restrict__ src,
                                                 const int* __restrict__ dst,
                                                 const int* __restrict__ C,
                                                 const int* __restrict__ totals,
                                                 int* __restrict__ bk_ptr,
                                                 unsigned* __restrict__ ebuf, int e) {
    __shared__ int bkL[NBK + 1];
    __shared__ int part[256];
    __shared__ int cur[NBK];
    const int t = threadIdx.x;

    int v[4];
    int s = 0;
    const int base = t * 4;
#pragma unroll
    for (int i = 0; i < 4; ++i) {
        int idx = base + i;
        v[i] = (idx < NBK) ? totals[idx] : 0;
        s += v[i];
    }
    part[t] = s;
    __syncthreads();
#pragma unroll
    for (int off = 1; off < 256; off <<= 1) {
        int x = part[t];
        int a = (t >= off) ? part[t - off] : 0;
        __syncthreads();
        part[t] = x + a;
        __syncthreads();
    }
    int run = part[t] - s;
#pragma unroll
    for (int i = 0; i < 4; ++i) {
        int idx = base + i;
        if (idx <= NBK) bkL[idx] = run;
        run += v[i];
    }
    __syncthreads();

    const int blk = blockIdx.x;
    for (int b = t; b < NBK; b += 256) cur[b] = bkL[b] + C[b * NCHUNK + blk];
    if (blk == 0)
        for (int i = t; i <= NBK; i += 256) bk_ptr[i] = bkL[i];
    __syncthreads();

    const int beg = blk * CH, end = min(beg + CH, e);
    for (int i = beg + t; i < end; i += 256) {
        int d = dst[i];
        int b = d >> BK_SHIFT;
        int pos = atomicAdd(&cur[b], 1);   // LDS atomic
        ebuf[pos] = ((unsigned)(d & 63) << 16) | (unsigned)src[i];  // NN < 65536
    }
}

// one block per bucket: LDS counting-sort by local dst; u16 coalesced outputs
__global__ __launch_bounds__(256) void k_bsort(const unsigned* __restrict__ ebuf,
                                               const int* __restrict__ bk_ptr,
                                               int* __restrict__ row_ptr,
                                               float* __restrict__ dinv,
                                               unsigned short* __restrict__ src16, int n) {
    __shared__ unsigned eL[BK_CAP];
    __shared__ unsigned short outL[BK_CAP];
    __shared__ int curL[64];
    __shared__ int baseL[64];

    const int b   = blockIdx.x;
    const int beg = bk_ptr[b];
    const int m   = bk_ptr[b + 1] - beg;
    const int t   = threadIdx.x;

    if (t < 64) curL[t] = 0;
    __syncthreads();

    for (int i = t; i < m; i += 256) {
        unsigned v = ebuf[beg + i];
        eL[i] = v;
        atomicAdd(&curL[v >> 16], 1);
    }
    __syncthreads();

    if (t < 64) {
        int c = curL[t];
        int x = c;
#pragma unroll
        for (int off = 1; off < 64; off <<= 1) {
            int y = __shfl_up(x, off);
            if (t >= off) x += y;
        }
        int excl = x - c;
        baseL[t] = excl;
        int d0 = (b << BK_SHIFT) + t;
        if (d0 < n) {
            row_ptr[d0] = beg + excl;
            dinv[d0]    = rsqrtf((float)(c + 1));   // +1 self-loop
        }
    }
    __syncthreads();
    if (t < 64) curL[t] = baseL[t];
    __syncthreads();

    for (int i = t; i < m; i += 256) {
        unsigned v = eL[i];
        int p = atomicAdd(&curL[v >> 16], 1);
        outL[p] = (unsigned short)(v & 0xFFFFu);
    }
    __syncthreads();
    for (int i = t; i < m; i += 256) src16[beg + i] = outL[i];
}

// ---------------- GEMM 1: Hsl[8][n][16] = bf16( dinv * (X f32 @ W1) ), sliced ----------------

__global__ __launch_bounds__(256) void k_gemm1(const float* __restrict__ X,
                                               const float* __restrict__ W,
                                               const float* __restrict__ dinv,
                                               unsigned short* __restrict__ Hsl, int n) {
    __shared__ float ws[DI * DH];       // 36.9 KB
    __shared__ float xs[32 * DI];       // 12.3 KB; aliased as hout (u16) after k-loop
    unsigned short* hout = reinterpret_cast<unsigned short*>(xs);

    const int tid  = threadIdx.x;
    const int row0 = blockIdx.x * 32;

    for (int i = tid; i < DI * DH; i += 256) ws[i] = W[i];
    {
        const float4* Xv = reinterpret_cast<const float4*>(X + (size_t)row0 * DI);
        float4* xv = reinterpret_cast<float4*>(xs);
        const int nv = 32 * DI / 4;
        const int maxv = ((n - row0) * DI) / 4;
        for (int i = tid; i < nv; i += 256)
            xv[i] = (i < maxv) ? Xv[i] : float4{0.f, 0.f, 0.f, 0.f};
    }
    __syncthreads();

    const int cg = tid & 15, rg = tid >> 4;
    float acc[2][6] = {};
    for (int k = 0; k < DI; ++k) {
        float x0 = xs[(rg * 2 + 0) * DI + k];
        float x1 = xs[(rg * 2 + 1) * DI + k];
#pragma unroll
        for (int j = 0; j < 6; ++j) {
            float wv = ws[k * DH + cg * 6 + j];
            acc[0][j] += x0 * wv;
            acc[1][j] += x1 * wv;
        }
    }
    __syncthreads();   // xs reads done

#pragma unroll
    for (int i = 0; i < 2; ++i) {
        int row = row0 + rg * 2 + i;
        float dv = (row < n) ? dinv[row] : 0.f;
#pragma unroll
        for (int j = 0; j < 6; ++j)
            hout[(rg * 2 + i) * 96 + cg * 6 + j] = f2bf(acc[i][j] * dv);
    }
    __syncthreads();

    // sliced write: thread -> (slice s = tid>>5, local row r = tid&31), 32B row
    {
        int s = tid >> 5, r = tid & 31;
        int row = row0 + r;
        if (row < n) {
            us8 lo, hi;
#pragma unroll
            for (int j = 0; j < 8; ++j) lo[j] = hout[r * 96 + s * 12 + j];
#pragma unroll
            for (int j = 0; j < 4; ++j) hi[j] = hout[r * 96 + s * 12 + 8 + j];
#pragma unroll
            for (int j = 4; j < 8; ++j) hi[j] = 0;
            us8* dst = reinterpret_cast<us8*>(Hsl + ((size_t)s * n + row) * 16);
            dst[0] = lo;
            dst[1] = hi;
        }
    }
}

// ---------------- GEMM 2: Hsl[8][n][8] = bf16( dinv * (A1sl bf16 @ W2) ), sliced ----------------

__global__ __launch_bounds__(256) void k_gemm2(const unsigned short* __restrict__ Asl,
                                               const float* __restrict__ W,
                                               const float* __restrict__ dinv,
                                               unsigned short* __restrict__ Hsl, int n) {
    __shared__ float ws[DH * DO];             // 18.4 KB
    __shared__ unsigned short xs[32 * DH];    // 6.1 KB; aliased as hout after
    const int tid  = threadIdx.x;
    const int row0 = blockIdx.x * 32;

    for (int i = tid; i < DH * DO; i += 256) ws[i] = W[i];
    {
        int r = tid >> 3, s = tid & 7;        // 32 rows x 8 slices
        int row = row0 + r;
        us4 a, b, c;
        if (row < n) {
            const us4* src = reinterpret_cast<const us4*>(Asl + ((size_t)s * n + row) * 16);
            a = src[0]; b = src[1]; c = src[2];
        } else {
            a = (us4)(0); b = (us4)(0); c = (us4)(0);
        }
        us4* d = reinterpret_cast<us4*>(xs + r * DH + s * 12);
        d[0] = a; d[1] = b; d[2] = c;
    }
    __syncthreads();

    const int cg = tid & 15, rg = tid >> 4;
    float acc[2][3] = {};
    for (int k = 0; k < DH; ++k) {
        float x0 = bf2f(xs[(rg * 2 + 0) * DH + k]);
        float x1 = bf2f(xs[(rg * 2 + 1) * DH + k]);
#pragma unroll
        for (int j = 0; j < 3; ++j) {
            float wv = ws[k * DO + cg * 3 + j];
            acc[0][j] += x0 * wv;
            acc[1][j] += x1 * wv;
        }
    }
    __syncthreads();

    unsigned short* hout = xs;
#pragma unroll
    for (int i = 0; i < 2; ++i) {
        int row = row0 + rg * 2 + i;
        float dv = (row < n) ? dinv[row] : 0.f;
#pragma unroll
        for (int j = 0; j < 3; ++j)
            hout[(rg * 2 + i) * 48 + cg * 3 + j] = f2bf(acc[i][j] * dv);
    }
    __syncthreads();

    {
        int s = tid >> 5, r = tid & 31;
        int row = row0 + r;
        if (row < n) {
            us8 v;
#pragma unroll
            for (int j = 0; j < 6; ++j) v[j] = hout[r * 48 + s * 6 + j];
            v[6] = 0; v[7] = 0;
            *reinterpret_cast<us8*>(Hsl + ((size_t)s * n + row) * 8) = v;
        }
    }
}

// ---------------- sliced CSR aggregation ----------------
// blockIdx%8 = slice (XCD-pinned). out[d][dims(slice)] = dinv[d]*(h'[d]+sum h'[s]) + b

template<int SD, int RW, bool RELU, bool OUTSLICED>
__global__ __launch_bounds__(256) void k_agg_sl(const unsigned short* __restrict__ hsl,
                                                const float* __restrict__ dinv,
                                                const int* __restrict__ row_ptr,
                                                const unsigned short* __restrict__ src16,
                                                const float* __restrict__ bias,
                                                void* __restrict__ outp, int n) {
    const int slice = blockIdx.x & 7;
    const int node  = (blockIdx.x >> 3) * 256 + threadIdx.x;
    if (node >= n) return;
    const unsigned short* hs = hsl + (size_t)slice * n * RW;

    float acc[SD];
    if (SD == 12) {
        const us8 lo = *reinterpret_cast<const us8*>(hs + (size_t)node * 16);
        const us4 hi = *reinterpret_cast<const us4*>(hs + (size_t)node * 16 + 8);
#pragma unroll
        for (int j = 0; j < 8; ++j) acc[j] = bf2f(lo[j]);
#pragma unroll
        for (int j = 0; j < 4; ++j) acc[8 + j] = bf2f(hi[j]);
    } else {
        const us8 v = *reinterpret_cast<const us8*>(hs + (size_t)node * 8);
#pragma unroll
        for (int j = 0; j < SD; ++j) acc[j] = bf2f(v[j]);
    }

    const int beg = row_ptr[node];
    const int end = row_ptr[node + 1];
    int k = beg;
    for (; k + 4 <= end; k += 4) {
        int s0 = src16[k + 0];
        int s1 = src16[k + 1];
        int s2 = src16[k + 2];
        int s3 = src16[k + 3];
        if (SD == 12) {
            const us8 a0 = *reinterpret_cast<const us8*>(hs + (size_t)s0 * 16);
            const us8 a1 = *reinterpret_cast<const us8*>(hs + (size_t)s1 * 16);
            const us8 a2 = *reinterpret_cast<const us8*>(hs + (size_t)s2 * 16);
            const us8 a3 = *reinterpret_cast<const us8*>(hs + (size_t)s3 * 16);
            const us4 b0 = *reinterpret_cast<const us4*>(hs + (size_t)s0 * 16 + 8);
            const us4 b1 = *reinterpret_cast<const us4*>(hs + (size_t)s1 * 16 + 8);
            const us4 b2 = *reinterpret_cast<const us4*>(hs + (size_t)s2 * 16 + 8);
            const us4 b3 = *reinterpret_cast<const us4*>(hs + (size_t)s3 * 16 + 8);
#pragma unroll
            for (int j = 0; j < 8; ++j)
                acc[j] += (bf2f(a0[j]) + bf2f(a1[j])) + (bf2f(a2[j]) + bf2f(a3[j]));
#pragma unroll
            for (int j = 0; j < 4; ++j)
                acc[8 + j] += (bf2f(b0[j]) + bf2f(b1[j])) + (bf2f(b2[j]) + bf2f(b3[j]));
        } else {
            const us8 a0 = *reinterpret_cast<const us8*>(hs + (size_t)s0 * 8);
            const us8 a1 = *reinterpret_cast<const us8*>(hs + (size_t)s1 * 8);
            const us8 a2 = *reinterpret_cast<const us8*>(hs + (size_t)s2 * 8);
            const us8 a3 = *reinterpret_cast<const us8*>(hs + (size_t)s3 * 8);
#pragma unroll
            for (int j = 0; j < SD; ++j)
                acc[j] += (bf2f(a0[j]) + bf2f(a1[j])) + (bf2f(a2[j]) + bf2f(a3[j]));
        }
    }
    for (; k < end; ++k) {
        int s = src16[k];
        if (SD == 12) {
            const us8 a = *reinterpret_cast<const us8*>(hs + (size_t)s * 16);
            const us4 b = *reinterpret_cast<const us4*>(hs + (size_t)s * 16 + 8);
#pragma unroll
            for (int j = 0; j < 8; ++j) acc[j] += bf2f(a[j]);
#pragma unroll
            for (int j = 0; j < 4; ++j) acc[8 + j] += bf2f(b[j]);
        } else {
            const us8 a = *reinterpret_cast<const us8*>(hs + (size_t)s * 8);
#pragma unroll
            for (int j = 0; j < SD; ++j) acc[j] += bf2f(a[j]);
        }
    }

    const float di = dinv[node];
    float r[SD];
#pragma unroll
    for (int j = 0; j < SD; ++j) {
        r[j] = di * acc[j] + bias[slice * SD + j];
        if (RELU) r[j] = fmaxf(r[j], 0.f);
    }

    if (OUTSLICED) {   // bf16, slice-major [8][n][16]
        unsigned short* o = (unsigned short*)outp + ((size_t)slice * n + node) * 16;
        us8 lo;
        us4 hi;
#pragma unroll
        for (int j = 0; j < 8; ++j) lo[j] = f2bf(r[j]);
#pragma unroll
        for (int j = 0; j < 4; ++j) hi[j] = f2bf(r[8 + j]);
        *reinterpret_cast<us8*>(o) = lo;
        *reinterpret_cast<us4*>(o + 8) = hi;
        *reinterpret_cast<us4*>(o + 12) = (us4)(0);
    } else {           // final f32 dense [n][48]
        float* o = (float*)outp + (size_t)node * DO + slice * SD;
#pragma unroll
        for (int j = 0; j < SD / 2; ++j)
            *reinterpret_cast<float2*>(o + j * 2) = float2{r[j * 2], r[j * 2 + 1]};
    }
}

// ---------------- launch ----------------

extern "C" void kernel_launch(void* const* d_in, const int* in_sizes, int n_in,
                              void* d_out, int out_size, void* d_ws, size_t ws_size,
                              hipStream_t stream) {
    const float* x   = (const float*)d_in[0];
    const int*   ei  = (const int*)d_in[1];   // [2][NE] int32
    const float* W1  = (const float*)d_in[2];
    const float* b1  = (const float*)d_in[3];
    const float* W2  = (const float*)d_in[4];
    const float* b2  = (const float*)d_in[5];
    float*       out = (float*)d_out;

    const int* srcv = ei;
    const int* dstv = ei + NE;

    // workspace (all blocks 32B-aligned)
    char* p = (char*)d_ws;
    float*          dinv  = (float*)p;           p += (size_t)NN * 4;
    unsigned short* a1sl  = (unsigned short*)p;  p += (size_t)8 * NN * 16 * 2;  // 12.8MB
    unsigned short* h1sl  = (unsigned short*)p;  p += (size_t)8 * NN * 16 * 2;  // 12.8MB (h2sl reuses)
    int*      row_ptr     = (int*)p;             p += (size_t)(NN + 16) * 4;
    unsigned short* src16 = (unsigned short*)p;  p += (size_t)NE * 2;
    unsigned* ebuf        = (unsigned*)p;        p += (size_t)NE * 4;
    int*      Cm          = (int*)p;             p += (size_t)NBK * NCHUNK * 4;
    int*      totals      = (int*)p;             p += (size_t)NBK * 4;
    int*      bk_ptr      = (int*)p;             p += (size_t)(NBK + 1) * 4;

    const int B = 256;
    const int NCH_NODES = (NN + 255) / 256;      // 196 node chunks for agg

    // CSR build (no global atomics)
    k_hist<<<NCHUNK, B, 0, stream>>>(dstv, Cm, NE);
    k_rowscan<<<(NBK + 3) / 4, B, 0, stream>>>(Cm, totals, row_ptr);
    k_scatter<<<NCHUNK, B, 0, stream>>>(srcv, dstv, Cm, totals, bk_ptr, ebuf, NE);
    k_bsort<<<NBK, B, 0, stream>>>(ebuf, bk_ptr, row_ptr, dinv, src16, NN);

    // layer 1
    k_gemm1<<<(NN + 31) / 32, B, 0, stream>>>(x, W1, dinv, h1sl, NN);
    k_agg_sl<12, 16, true, true><<<NCH_NODES * 8, B, 0, stream>>>(
        h1sl, dinv, row_ptr, src16, b1, a1sl, NN);

    // layer 2 (h2sl reuses h1sl's buffer)
    unsigned short* h2sl = h1sl;
    k_gemm2<<<(NN + 31) / 32, B, 0, stream>>>(a1sl, W2, dinv, h2sl, NN);
    k_agg_sl<6, 8, false, false><<<NCH_NODES * 8, B, 0, stream>>>(
        h2sl, dinv, row_ptr, src16, b2, out, NN);
}

// Round 9
// 123.927 us; speedup vs baseline: 1.4354x; 1.4354x over previous
//
#include <hip/hip_runtime.h>
#include <hip/hip_bf16.h>

// GCN: out = GCNConv2( relu( GCNConv1(x) ) )
// Round 8->9: revert to DENSE h layout (round 7; sliced layout killed traffic
// but broke intra-wave coalescing: 64 unique lines/wave-instr, request-bound).
// Dense agg now 8-deep gather pipeline (u16 indices loaded 8-at-a-time),
// NCHUNK 128->256 for build parallelism.

constexpr int NN = 50000;
constexpr int NE = 800000;
constexpr int DI = 96;
constexpr int DH = 96;
constexpr int DO = 48;

constexpr int BK_SHIFT = 6;                  // 64 dst nodes per bucket
constexpr int NBK      = (NN + 63) >> 6;     // 782 buckets, ~1023 edges each
constexpr int BK_CAP   = 2048;               // >> max bucket load

constexpr int NCHUNK = 256;                  // blocks in hist/scatter
constexpr int CH     = (NE + NCHUNK - 1) / NCHUNK;  // 3125 edges per chunk

typedef unsigned short us8 __attribute__((ext_vector_type(8)));

__device__ __forceinline__ float bf2f(unsigned short u) {
    return __uint_as_float(((unsigned int)u) << 16);
}
__device__ __forceinline__ unsigned short f2bf(float f) {
    __hip_bfloat16 b = __float2bfloat16(f);
    return *reinterpret_cast<unsigned short*>(&b);
}

// ---------------- CSR build (atomic-free multisplit) ----------------

// per-chunk LDS histogram -> transposed counts C[bucket][chunk]
__global__ __launch_bounds__(256) void k_hist(const int* __restrict__ dst,
                                              int* __restrict__ C, int e) {
    __shared__ int hist[NBK];
    for (int i = threadIdx.x; i < NBK; i += 256) hist[i] = 0;
    __syncthreads();
    const int blk = blockIdx.x;
    const int beg = blk * CH, end = min(beg + CH, e);
    for (int i = beg + threadIdx.x; i < end; i += 256)
        atomicAdd(&hist[dst[i] >> BK_SHIFT], 1);
    __syncthreads();
    for (int b = threadIdx.x; b < NBK; b += 256)
        C[b * NCHUNK + blk] = hist[b];
}

// wave-per-bucket: exclusive scan of C[r][0..255] in place, row total out
__global__ __launch_bounds__(256) void k_rowscan(int* __restrict__ C,
                                                 int* __restrict__ totals,
                                                 int* __restrict__ row_ptr) {
    if (blockIdx.x == 0 && threadIdx.x == 0) row_ptr[NN] = NE;  // sentinel
    const int w    = threadIdx.x >> 6;
    const int lane = threadIdx.x & 63;
    const int r    = blockIdx.x * 4 + w;
    if (r >= NBK) return;
    int* row = C + r * NCHUNK;
    int v[4], s[4];
#pragma unroll
    for (int q = 0; q < 4; ++q) { v[q] = row[q * 64 + lane]; s[q] = v[q]; }
#pragma unroll
    for (int off = 1; off < 64; off <<= 1) {
#pragma unroll
        for (int q = 0; q < 4; ++q) {
            int y = __shfl_up(s[q], off);
            if (lane >= off) s[q] += y;
        }
    }
    // carry chain across the four 64-segments
    int c0 = __shfl(s[0], 63);
    int c1 = __shfl(s[1], 63);
    int c2 = __shfl(s[2], 63);
    s[1] += c0;
    s[2] += c0 + c1;
    s[3] += c0 + c1 + c2;
#pragma unroll
    for (int q = 0; q < 4; ++q) row[q * 64 + lane] = s[q] - v[q];  // exclusive
    if (lane == 63) totals[r] = s[3];
}

// scatter: in-LDS scan of totals -> bucket bases; LDS cursors; no global atomics.
// block 0 additionally publishes bk_ptr for k_bsort.
__global__ __launch_bounds__(256) void k_scatter(const int* __restrict__ src,
                                                 const int* __restrict__ dst,
                                                 const int* __restrict__ C,
                                                 const int* __restrict__ totals,
                                                 int* __restrict__ bk_ptr,
                                                 unsigned* __restrict__ ebuf, int e) {
    __shared__ int bkL[NBK + 1];
    __shared__ int part[256];
    __shared__ int cur[NBK];
    const int t = threadIdx.x;

    int v[4];
    int s = 0;
    const int base = t * 4;
#pragma unroll
    for (int i = 0; i < 4; ++i) {
        int idx = base + i;
        v[i] = (idx < NBK) ? totals[idx] : 0;
        s += v[i];
    }
    part[t] = s;
    __syncthreads();
#pragma unroll
    for (int off = 1; off < 256; off <<= 1) {
        int x = part[t];
        int a = (t >= off) ? part[t - off] : 0;
        __syncthreads();
        part[t] = x + a;
        __syncthreads();
    }
    int run = part[t] - s;
#pragma unroll
    for (int i = 0; i < 4; ++i) {
        int idx = base + i;
        if (idx <= NBK) bkL[idx] = run;
        run += v[i];
    }
    __syncthreads();

    const int blk = blockIdx.x;
    for (int b = t; b < NBK; b += 256) cur[b] = bkL[b] + C[b * NCHUNK + blk];
    if (blk == 0)
        for (int i = t; i <= NBK; i += 256) bk_ptr[i] = bkL[i];
    __syncthreads();

    const int beg = blk * CH, end = min(beg + CH, e);
    for (int i = beg + t; i < end; i += 256) {
        int d = dst[i];
        int b = d >> BK_SHIFT;
        int pos = atomicAdd(&cur[b], 1);   // LDS atomic, short chains
        ebuf[pos] = ((unsigned)(d & 63) << 16) | (unsigned)src[i];  // NN < 65536
    }
}

// one block per bucket: LDS counting-sort by local dst; u16 coalesced outputs
__global__ __launch_bounds__(256) void k_bsort(const unsigned* __restrict__ ebuf,
                                               const int* __restrict__ bk_ptr,
                                               int* __restrict__ row_ptr,
                                               float* __restrict__ dinv,
                                               unsigned short* __restrict__ src16, int n) {
    __shared__ unsigned eL[BK_CAP];
    __shared__ unsigned short outL[BK_CAP];
    __shared__ int curL[64];
    __shared__ int baseL[64];

    const int b   = blockIdx.x;
    const int beg = bk_ptr[b];
    const int m   = bk_ptr[b + 1] - beg;
    const int t   = threadIdx.x;

    if (t < 64) curL[t] = 0;
    __syncthreads();

    for (int i = t; i < m; i += 256) {
        unsigned v = ebuf[beg + i];
        eL[i] = v;
        atomicAdd(&curL[v >> 16], 1);
    }
    __syncthreads();

    if (t < 64) {
        int c = curL[t];
        int x = c;
#pragma unroll
        for (int off = 1; off < 64; off <<= 1) {
            int y = __shfl_up(x, off);
            if (t >= off) x += y;
        }
        int excl = x - c;
        baseL[t] = excl;
        int d0 = (b << BK_SHIFT) + t;
        if (d0 < n) {
            row_ptr[d0] = beg + excl;
            dinv[d0]    = rsqrtf((float)(c + 1));   // +1 self-loop
        }
    }
    __syncthreads();
    if (t < 64) curL[t] = baseL[t];
    __syncthreads();

    for (int i = t; i < m; i += 256) {
        unsigned v = eL[i];
        int p = atomicAdd(&curL[v >> 16], 1);
        outL[p] = (unsigned short)(v & 0xFFFFu);
    }
    __syncthreads();
    for (int i = t; i < m; i += 256) src16[beg + i] = outL[i];
}

// ---------------- dense GEMM: H[n] = bf16( dinv[row] * (X[n] @ W) ) ----------------
// XBF16: input matrix stored bf16 (a1), else f32 (x).

template<int DOUT, bool XBF16>
__global__ __launch_bounds__(256) void k_gemm(const void* __restrict__ Xin,
                                              const float* __restrict__ W,
                                              const float* __restrict__ dinv,
                                              unsigned short* __restrict__ H, int n) {
    constexpr int ROWS = 32;
    constexpr int CPT  = DOUT / 16;
    constexpr int RPT  = 2;

    __shared__ float ws[DI * DOUT];
    __shared__ unsigned char xraw[ROWS * DI * (XBF16 ? 2 : 4)];
    float*          xsf = reinterpret_cast<float*>(xraw);
    unsigned short* xsu = reinterpret_cast<unsigned short*>(xraw);

    const int tid  = threadIdx.x;
    const int row0 = blockIdx.x * ROWS;

    for (int i = tid; i < DI * DOUT; i += 256) ws[i] = W[i];

    if (XBF16) {
        const us8* Xv = reinterpret_cast<const us8*>(
            (const unsigned short*)Xin + (size_t)row0 * DI);
        us8* xv = reinterpret_cast<us8*>(xsu);
        const int nv   = ROWS * DI / 8;
        const int maxv = ((n - row0) * DI) / 8;
        for (int i = tid; i < nv; i += 256)
            xv[i] = (i < maxv) ? Xv[i] : (us8)(0);
    } else {
        const float4* Xv = reinterpret_cast<const float4*>(
            (const float*)Xin + (size_t)row0 * DI);
        float4* xv = reinterpret_cast<float4*>(xsf);
        const int nv   = ROWS * DI / 4;
        const int maxv = ((n - row0) * DI) / 4;
        for (int i = tid; i < nv; i += 256)
            xv[i] = (i < maxv) ? Xv[i] : float4{0.f, 0.f, 0.f, 0.f};
    }
    __syncthreads();

    const int cg = tid & 15;
    const int rg = tid >> 4;

    float acc[RPT][CPT];
#pragma unroll
    for (int i = 0; i < RPT; ++i)
#pragma unroll
        for (int j = 0; j < CPT; ++j) acc[i][j] = 0.f;

    for (int k = 0; k < DI; ++k) {
        float xv[RPT];
#pragma unroll
        for (int i = 0; i < RPT; ++i) {
            int r = rg * RPT + i;
            xv[i] = XBF16 ? bf2f(xsu[r * DI + k]) : xsf[r * DI + k];
        }
#pragma unroll
        for (int j = 0; j < CPT; ++j) {
            float wv = ws[k * DOUT + cg * CPT + j];
#pragma unroll
            for (int i = 0; i < RPT; ++i) acc[i][j] += xv[i] * wv;
        }
    }

#pragma unroll
    for (int i = 0; i < RPT; ++i) {
        int row = row0 + rg * RPT + i;
        if (row < n) {
            float dv = dinv[row];
#pragma unroll
            for (int j = 0; j < CPT; ++j)
                H[(size_t)row * DOUT + cg * CPT + j] = f2bf(acc[i][j] * dv);
        }
    }
}

// ---------------- CSR aggregation over pre-scaled bf16 h' (dense layout) ----------------
// out[d] = dinv[d] * ( h'[d] + sum_{s in N(d)} h'[s] ) + bias ;  h' = dinv*h
// thread = (node, 8-dim group), G = D/8 lanes per node -> coalesced 16B row chunks.
// 8-deep gather pipeline: 8 u16 indices per load, 8 independent 16B gathers in flight.

template<int D, bool RELU, bool OUTBF16>
__global__ __launch_bounds__(256) void k_agg_csr(const unsigned short* __restrict__ h,
                                                 const float* __restrict__ dinv,
                                                 const int* __restrict__ row_ptr,
                                                 const unsigned short* __restrict__ src16,
                                                 const float* __restrict__ bias,
                                                 void* __restrict__ outp, int n) {
    constexpr int G = D / 8;
    int t = blockIdx.x * blockDim.x + threadIdx.x;
    if (t >= n * G) return;
    const int node = t / G;
    const int g    = t % G;

    const us8* h8 = reinterpret_cast<const us8*>(h);

    float accA[8], accB[8];
    {
        us8 hv = h8[(size_t)node * G + g];   // self term h'[node]
#pragma unroll
        for (int j = 0; j < 8; ++j) { accA[j] = bf2f(hv[j]); accB[j] = 0.f; }
    }

    const int beg = row_ptr[node];
    const int end = row_ptr[node + 1];
    int k = beg;
    // scalar head up to 8-alignment
    int kA = min((beg + 7) & ~7, end);
    for (; k < kA; ++k) {
        us8 vv = h8[(size_t)src16[k] * G + g];
#pragma unroll
        for (int j = 0; j < 8; ++j) accA[j] += bf2f(vv[j]);
    }
    // 8-wide main loop: one us8 index load, 8 gathers in flight
    for (; k + 8 <= end; k += 8) {
        us8 si = *reinterpret_cast<const us8*>(src16 + k);
        us8 v0 = h8[(size_t)si[0] * G + g];
        us8 v1 = h8[(size_t)si[1] * G + g];
        us8 v2 = h8[(size_t)si[2] * G + g];
        us8 v3 = h8[(size_t)si[3] * G + g];
        us8 v4 = h8[(size_t)si[4] * G + g];
        us8 v5 = h8[(size_t)si[5] * G + g];
        us8 v6 = h8[(size_t)si[6] * G + g];
        us8 v7 = h8[(size_t)si[7] * G + g];
#pragma unroll
        for (int j = 0; j < 8; ++j) {
            accA[j] += (bf2f(v0[j]) + bf2f(v1[j])) + (bf2f(v4[j]) + bf2f(v5[j]));
            accB[j] += (bf2f(v2[j]) + bf2f(v3[j])) + (bf2f(v6[j]) + bf2f(v7[j]));
        }
    }
    // tail
    for (; k < end; ++k) {
        us8 vv = h8[(size_t)src16[k] * G + g];
#pragma unroll
        for (int j = 0; j < 8; ++j) accB[j] += bf2f(vv[j]);
    }

    const float di = dinv[node];
    const float4* b4 = reinterpret_cast<const float4*>(bias);
    float4 b0 = b4[g * 2], b1 = b4[g * 2 + 1];
    float r[8];
#pragma unroll
    for (int j = 0; j < 8; ++j) r[j] = di * (accA[j] + accB[j]);
    r[0] += b0.x; r[1] += b0.y; r[2] += b0.z; r[3] += b0.w;
    r[4] += b1.x; r[5] += b1.y; r[6] += b1.z; r[7] += b1.w;
    if (RELU) {
#pragma unroll
        for (int j = 0; j < 8; ++j) r[j] = fmaxf(r[j], 0.f);
    }
    if (OUTBF16) {
        us8 o;
#pragma unroll
        for (int j = 0; j < 8; ++j) o[j] = f2bf(r[j]);
        reinterpret_cast<us8*>((unsigned short*)outp)[(size_t)node * G + g] = o;
    } else {
        float4* o4 = reinterpret_cast<float4*>((float*)outp + (size_t)node * D + g * 8);
        o4[0] = float4{r[0], r[1], r[2], r[3]};
        o4[1] = float4{r[4], r[5], r[6], r[7]};
    }
}

// ---------------- launch ----------------

extern "C" void kernel_launch(void* const* d_in, const int* in_sizes, int n_in,
                              void* d_out, int out_size, void* d_ws, size_t ws_size,
                              hipStream_t stream) {
    const float* x   = (const float*)d_in[0];
    const int*   ei  = (const int*)d_in[1];   // [2][NE] int32
    const float* W1  = (const float*)d_in[2];
    const float* b1  = (const float*)d_in[3];
    const float* W2  = (const float*)d_in[4];
    const float* b2  = (const float*)d_in[5];
    float*       out = (float*)d_out;

    const int* srcv = ei;
    const int* dstv = ei + NE;

    // workspace layout (16B alignment for vector arrays)
    char* p = (char*)d_ws;
    float*          dinv  = (float*)p;           p += (size_t)NN * 4;
    unsigned short* a1    = (unsigned short*)p;  p += (size_t)NN * DH * 2;   // bf16
    unsigned short* h1    = (unsigned short*)p;  p += (size_t)NN * DH * 2;   // bf16, reused as h2
    int*      row_ptr     = (int*)p;             p += (size_t)(NN + 16) * 4;
    unsigned short* src16 = (unsigned short*)p;  p += (size_t)NE * 2;
    unsigned* ebuf        = (unsigned*)p;        p += (size_t)NE * 4;
    int*      Cm          = (int*)p;             p += (size_t)NBK * NCHUNK * 4;
    int*      totals      = (int*)p;             p += (size_t)NBK * 4;
    int*      bk_ptr      = (int*)p;             p += (size_t)(NBK + 1) * 4;

    const int B = 256;

    // CSR build (no global atomics)
    k_hist<<<NCHUNK, B, 0, stream>>>(dstv, Cm, NE);
    k_rowscan<<<(NBK + 3) / 4, B, 0, stream>>>(Cm, totals, row_ptr);
    k_scatter<<<NCHUNK, B, 0, stream>>>(srcv, dstv, Cm, totals, bk_ptr, ebuf, NE);
    k_bsort<<<NBK, B, 0, stream>>>(ebuf, bk_ptr, row_ptr, dinv, src16, NN);

    // layer 1: h1 = bf16(dinv * (x@W1)) ; a1 = bf16(relu(dinv*(self+gather) + b1))
    k_gemm<DH, false><<<(NN + 31) / 32, B, 0, stream>>>(x, W1, dinv, h1, NN);
    {
        int total = NN * (DH / 8);
        k_agg_csr<DH, true, true><<<(total + B - 1) / B, B, 0, stream>>>(
            h1, dinv, row_ptr, src16, b1, a1, NN);
    }

    // layer 2: h2 = bf16(dinv * (a1@W2)) ; out = dinv*(self+gather) + b2
    unsigned short* h2 = h1;
    k_gemm<DO, true><<<(NN + 31) / 32, B, 0, stream>>>(a1, W2, dinv, h2, NN);
    {
        int total = NN * (DO / 8);
        k_agg_csr<DO, false, false><<<(total + B - 1) / B, B, 0, stream>>>(
            h2, dinv, row_ptr, src16, b2, out, NN);
    }
}